// Round 16
// baseline (343.782 us; speedup 1.0000x reference)
//
#include <hip/hip_runtime.h>
#include <hip/hip_bf16.h>
#include <stdint.h>

// D-MPNN encoder, fused per-molecule kernel (R15 base + single-msg-buffer to
// cut LDS 62->52 KB and unlock a 3rd resident block/CU).
// Graph facts: ring molecules, 24 atoms / 48 bonds each; other(b) in-molecule;
// a2b[v]={2v-1,2v}; molecule m owns atoms 1+24m.., bonds 1+48m..
// Ledger (counter-verified):
//   R4-R9: reg working set over cap -> scratch spills.
//   R6/R10: full-unroll k-loops -> 208 VGPR -> 1 wave/SIMD, 334 us.
//   R12: unroll-1 k-loops -> 104 VGPR -> 2 blocks/CU, 251 us.
//   R13: inp->acc-init + ping-pong + native cvt -> 227 us (VGPR 128).
//   R14: reg SW-pipeline -> 148 VGPR -> 1 block/CU, 297 us. Reverted.
//   R15: GEMM0 5 k-steps + vectorized staging -> 212 us (VGPR 128, occ 22%).
//   All rounds so far were LDS-capped at 2 blocks/CU (62 KB); >2 never tested.
//   R16 (this): ONE msg buffer, read->bar->write->bar per iteration (2 bar/it);
//   ain shrunk to [24][448] in its own region (GEMM3 pad rows read clamped
//   rows; outputs guard-discarded; D-rows depend only on their own A-rows).
//   LDS 52.4 KB -> 3 blocks/CU (157 KB), 3 waves/SIMD TLP.

typedef __attribute__((ext_vector_type(8))) short s8v;
typedef __attribute__((ext_vector_type(4))) float f4v;
typedef float f4u __attribute__((ext_vector_type(4), aligned(4)));  // unaligned-ok vec load

__device__ __forceinline__ float u2f(unsigned int u){
  union { unsigned int i; float f; } v; v.i = u; return v.f;
}
__device__ __forceinline__ unsigned short f2bf(float f){
  union { __hip_bfloat16 b; unsigned short u; } cv;
  cv.b = __float2bfloat16(f);           // hardware RNE
  return cv.u;
}
__device__ __forceinline__ float bf2f(unsigned short u){
  return u2f(((unsigned int)u)<<16);
}

// Build MFMA B-fragment layout: frag[ks][nf][lane][8],
//   element = W[k = ks*32 + (lane>>4)*8 + j][n = nf*16 + (lane&15)] (0 outside)
// remap=1 (W_o with concat padding): k<133 -> k, 133..143 -> 0, 144..443 -> k-11, else 0.
__global__ void conv_w_k(const float* __restrict__ W, unsigned short* __restrict__ frag,
                         int NS, int K0, int remap)
{
  int id = blockIdx.x*256 + threadIdx.x;
  int total = NS*20*64;
  if (id>=total) return;
  int lane = id & 63;
  int fid = id >> 6;
  int nf = fid % 20, ks = fid / 20;
  int n = nf*16 + (lane & 15);
  int kb = ks*32 + (lane>>4)*8;
  unsigned short o[8];
#pragma unroll
  for (int j=0;j<8;j++){
    int k = kb + j;
    int ksrc;
    if (remap){
      if (k < 133) ksrc = k;
      else if (k < 144) ksrc = -1;
      else if (k < 444) ksrc = k - 11;
      else ksrc = -1;
    } else {
      ksrc = (k < K0) ? k : -1;
    }
    float v = (ksrc >= 0 && n < 300) ? W[(size_t)ksrc*300 + n] : 0.f;
    o[j] = f2bf(v);
  }
  *(s8v*)(frag + (size_t)id*8) = *(const s8v*)o;
}

// Fused per-molecule MPNN. 256 threads = 4 waves (1M x 4N); per wave all M rows
// x 80 cols (5 nf). LDS: msg [48][320] bf16 (chunk^=row&7 swizzle; doubles as
// fb staging [48][192] and hid f32 [24][300]) + ain [24][448] + oth[48].
// inp residual in 30 packed-bf16 VGPRs, folded into acc init.
__global__ __launch_bounds__(256) void mpnn_fused(
    const float* __restrict__ f_atoms, const float* __restrict__ f_bonds,
    const int* __restrict__ a2b, const int* __restrict__ b2a,
    const int* __restrict__ b2revb,
    const unsigned short* __restrict__ wif, const unsigned short* __restrict__ whf,
    const unsigned short* __restrict__ wof, const float* __restrict__ b_o,
    float* __restrict__ out)
{
  __shared__ unsigned char L[52416];
  unsigned short* MB  = (unsigned short*)L;             // msg [48][320] swizzled
  unsigned short* ain = (unsigned short*)(L + 30720);   // [24][448] swizzled
  int* oth = (int*)(L + 52224);                         // [48]
  float* hid = (float*)L;                               // [24][300] f32 (aliases MB)

  const int tid  = threadIdx.x;
  const int lane = tid & 63;
  const int w    = tid >> 6;
  const int lrow = lane & 15;
  const int kq   = lane >> 4;
  const int wn0  = w*5;
  const int blk  = blockIdx.x;
  const int gb0  = 48*blk + 1;   // first global bond of this molecule
  const int ga0  = 24*blk + 1;   // first global atom

  // ---- per-bond "other" index (local) ----
  if (tid < 48){
    int gb = gb0 + tid;
    int u = b2a[gb];
    oth[tid] = a2b[2*u] + a2b[2*u+1] - b2revb[gb] - gb0;
  }
  // ---- stage f_bonds -> bf16 LDS MB [48][24 chunks], swizzled ----
  for (int c = tid; c < 48*24; c += 256){
    int row = c/24, ch = c - row*24;
    const float* sp = f_bonds + (size_t)(gb0+row)*147 + ch*8;
    unsigned short o[8];
    if (ch < 18){
      f4u v0 = *(const f4u*)(sp);
      f4u v1 = *(const f4u*)(sp+4);
#pragma unroll
      for (int j=0;j<4;j++){ o[j] = f2bf(v0[j]); o[4+j] = f2bf(v1[j]); }
    } else if (ch == 18){
#pragma unroll
      for (int j=0;j<8;j++) o[j] = f2bf((144+j) < 147 ? sp[j] : 0.f);
    } else {
#pragma unroll
      for (int j=0;j<8;j++) o[j] = 0;
    }
    *(s8v*)(MB + (size_t)row*192 + (((ch^(row&7))<<3))) = *(const s8v*)o;
  }
  __syncthreads();

  // ---- GEMM0: inp = fb @ W_i  (K_real=147 -> 5 k-steps), fb in MB ----
  f4v acc[3][5];
#pragma unroll
  for (int mf=0;mf<3;mf++)
#pragma unroll
    for (int n=0;n<5;n++) acc[mf][n] = (f4v){0.f,0.f,0.f,0.f};

#pragma unroll 1
  for (int ks=0; ks<5; ks++){
    const unsigned short* wp = wif + ((size_t)(ks*20 + wn0)*64 + lane)*8;
    s8v bfr[5];
#pragma unroll
    for (int n=0;n<5;n++) bfr[n] = *(const s8v*)(wp + n*512);
    s8v af[3];
#pragma unroll
    for (int mf=0;mf<3;mf++){
      int row = mf*16 + lrow;
      af[mf] = *(const s8v*)(MB + (size_t)row*192 + (((ks*4+kq)^(row&7))<<3));
    }
#pragma unroll
    for (int n=0;n<5;n++)
#pragma unroll
      for (int mf=0;mf<3;mf++)
        acc[mf][n] = __builtin_amdgcn_mfma_f32_16x16x32_bf16(af[mf], bfr[n], acc[mf][n], 0,0,0);
  }
  __syncthreads();   // all fb reads done; MB reusable as msg

  // ---- inp -> packed-bf16 regs; msg0 = relu(inp) -> MB ----
  unsigned int inpP0[3][5], inpP1[3][5];   // [r0|r1<<16], [r2|r3<<16]
#pragma unroll
  for (int mf=0;mf<3;mf++){
#pragma unroll
    for (int n=0;n<5;n++){
      inpP0[mf][n] = (unsigned)f2bf(acc[mf][n][0]) | ((unsigned)f2bf(acc[mf][n][1])<<16);
      inpP1[mf][n] = (unsigned)f2bf(acc[mf][n][2]) | ((unsigned)f2bf(acc[mf][n][3])<<16);
      int col = (wn0+n)*16 + lrow;
#pragma unroll
      for (int r=0;r<4;r++){
        int row = mf*16 + kq*4 + r;
        float v = acc[mf][n][r];
        MB[(size_t)row*320 + (((col>>3)^(row&7))<<3) + (col&7)] = f2bf(v>0.f ? v : 0.f);
      }
    }
  }
  __syncthreads();

  const int g0 = oth[lrow], g1 = oth[16+lrow], g2 = oth[32+lrow];

  // ---- 5 message-update iterations, single buffer, 2 barriers each ----
#pragma unroll 1
  for (int it=0; it<5; ++it){
    // acc init = inp residual
#pragma unroll
    for (int mf=0;mf<3;mf++)
#pragma unroll
      for (int n=0;n<5;n++){
        unsigned int p0 = inpP0[mf][n], p1 = inpP1[mf][n];
        acc[mf][n][0] = u2f(p0<<16);
        acc[mf][n][1] = u2f(p0 & 0xffff0000u);
        acc[mf][n][2] = u2f(p1<<16);
        acc[mf][n][3] = u2f(p1 & 0xffff0000u);
      }

#pragma unroll 1
    for (int ks=0; ks<10; ks++){
      const unsigned short* wp = whf + ((size_t)(ks*20 + wn0)*64 + lane)*8;
      s8v bfr[5];
#pragma unroll
      for (int n=0;n<5;n++) bfr[n] = *(const s8v*)(wp + n*512);
      s8v af[3];
      af[0] = *(const s8v*)(MB + (size_t)g0*320 + (((ks*4+kq)^(g0&7))<<3));
      af[1] = *(const s8v*)(MB + (size_t)g1*320 + (((ks*4+kq)^(g1&7))<<3));
      af[2] = *(const s8v*)(MB + (size_t)g2*320 + (((ks*4+kq)^(g2&7))<<3));
#pragma unroll
      for (int n=0;n<5;n++)
#pragma unroll
        for (int mf=0;mf<3;mf++)
          acc[mf][n] = __builtin_amdgcn_mfma_f32_16x16x32_bf16(af[mf], bfr[n], acc[mf][n], 0,0,0);
    }
    __syncthreads();   // all old-msg reads complete before overwrite
    // epilogue: msg_new = relu(acc) -> same buffer
#pragma unroll
    for (int mf=0;mf<3;mf++){
#pragma unroll
      for (int n=0;n<5;n++){
        int col = (wn0+n)*16 + lrow;
#pragma unroll
        for (int r=0;r<4;r++){
          int row = mf*16 + kq*4 + r;
          float v = acc[mf][n][r];
          MB[(size_t)row*320 + (((col>>3)^(row&7))<<3) + (col&7)] = f2bf(v>0.f ? v : 0.f);
        }
      }
    }
    __syncthreads();
  }

  // ---- stage a_in = [f_atoms | 0 | amsg] into ain [24][56 ch], swizzled ----
  for (int c = tid; c < 24*56; c += 256){
    int row = c/56, ch = c - row*56;
    unsigned short o[8];
#pragma unroll
    for (int j=0;j<8;j++) o[j] = 0;
    if (ch < 16){
      const float* ap = f_atoms + (size_t)(ga0+row)*133 + ch*8;
      f4u v0 = *(const f4u*)(ap);
      f4u v1 = *(const f4u*)(ap+4);
#pragma unroll
      for (int j=0;j<4;j++){ o[j] = f2bf(v0[j]); o[4+j] = f2bf(v1[j]); }
    } else if (ch == 16){
      const float* ap = f_atoms + (size_t)(ga0+row)*133 + 128;
#pragma unroll
      for (int j=0;j<8;j++) o[j] = f2bf((128+j) < 133 ? ap[j] : 0.f);
    } else if (ch >= 18){
      int q = ch - 18;
      int r2 = 2*row, r3 = 2*row+1;
      s8v a = *(const s8v*)(MB + (size_t)r2*320 + ((q^(r2&7))<<3));
      s8v b = *(const s8v*)(MB + (size_t)r3*320 + ((q^(r3&7))<<3));
#pragma unroll
      for (int j=0;j<8;j++)
        o[j] = f2bf(bf2f((unsigned short)a[j]) + bf2f((unsigned short)b[j]));
    }
    *(s8v*)(ain + (size_t)row*448 + ((ch^(row&7))<<3)) = *(const s8v*)o;
  }
  __syncthreads();

  // ---- GEMM3: hid = relu(a_in @ W_o + b_o)  (K=448, 14 k-steps) ----
  // mf=1 rows 24-31 read clamped in-bounds rows (outputs discarded; each
  // D-row depends only on its own A-row, so kept rows are unaffected).
  const int r1 = 16 + lrow;
  const int r1c = (r1 < 24) ? r1 : (r1 - 16);
  f4v acc2[2][5];
#pragma unroll
  for (int mf=0;mf<2;mf++)
#pragma unroll
    for (int n=0;n<5;n++) acc2[mf][n] = (f4v){0.f,0.f,0.f,0.f};

#pragma unroll 1
  for (int ks=0; ks<14; ks++){
    const unsigned short* wp = wof + ((size_t)(ks*20 + wn0)*64 + lane)*8;
    s8v bfr[5];
#pragma unroll
    for (int n=0;n<5;n++) bfr[n] = *(const s8v*)(wp + n*512);
    s8v af[2];
    af[0] = *(const s8v*)(ain + (size_t)lrow*448 + (((ks*4+kq)^(lrow&7))<<3));
    af[1] = *(const s8v*)(ain + (size_t)r1c*448 + (((ks*4+kq)^(r1c&7))<<3));
#pragma unroll
    for (int n=0;n<5;n++)
#pragma unroll
      for (int mf=0;mf<2;mf++)
        acc2[mf][n] = __builtin_amdgcn_mfma_f32_16x16x32_bf16(af[mf], bfr[n], acc2[mf][n], 0,0,0);
  }
  // MB fully consumed (last readers: ain staging, barrier passed) -> hid f32
#pragma unroll
  for (int mf=0;mf<2;mf++){
#pragma unroll
    for (int n=0;n<5;n++){
      int col = (wn0+n)*16 + lrow;
      if (col < 300){
        float bo = b_o[col];
#pragma unroll
        for (int r=0;r<4;r++){
          int row = mf*16 + kq*4 + r;
          if (row < 24){
            float v = acc2[mf][n][r] + bo;
            hid[row*300 + col] = v>0.f ? v : 0.f;
          }
        }
      }
    }
  }
  __syncthreads();

  // ---- per-molecule mean over 24 atoms ----
  for (int c = tid; c < 300; c += 256){
    float s = 0.f;
#pragma unroll
    for (int a=0;a<24;a++) s += hid[a*300 + c];
    out[(size_t)blk*300 + c] = s * (1.0f/24.0f);
  }
}

extern "C" void kernel_launch(void* const* d_in, const int* in_sizes, int n_in,
                              void* d_out, int out_size, void* d_ws, size_t ws_size,
                              hipStream_t stream)
{
  const float* f_atoms = (const float*)d_in[0];
  const float* f_bonds = (const float*)d_in[1];
  const int* a2b    = (const int*)d_in[2];
  const int* b2a    = (const int*)d_in[4];
  const int* b2revb = (const int*)d_in[5];
  const float* W_i = (const float*)d_in[8];
  const float* W_h = (const float*)d_in[9];
  const float* W_o = (const float*)d_in[10];
  const float* b_o = (const float*)d_in[11];

  const int NA   = in_sizes[2] / 2;   // 49153 (incl dummy atom 0)
  const int MOLS = (NA - 1) / 24;     // 2048

  // workspace: W fragment buffers only (~600 KB)
  unsigned short* wif = (unsigned short*)d_ws;               // 5 k-steps
  unsigned short* whf = wif + (size_t)5*20*64*8;             // 10 k-steps
  unsigned short* wof = whf + (size_t)10*20*64*8;            // 14 k-steps
  (void)ws_size; (void)n_in; (void)out_size;

  hipLaunchKernelGGL(conv_w_k, dim3((5*20*64+255)/256),  dim3(256), 0, stream, W_i, wif, 5, 147, 0);
  hipLaunchKernelGGL(conv_w_k, dim3((10*20*64+255)/256), dim3(256), 0, stream, W_h, whf, 10, 300, 0);
  hipLaunchKernelGGL(conv_w_k, dim3((14*20*64+255)/256), dim3(256), 0, stream, W_o, wof, 14, 433, 1);

  hipLaunchKernelGGL(mpnn_fused, dim3(MOLS), dim3(256), 0, stream,
                     f_atoms, f_bonds, a2b, b2a, b2revb,
                     wif, whf, wof, b_o, (float*)d_out);
}

// Round 17
// 332.620 us; speedup vs baseline: 1.0336x; 1.0336x over previous
//
#include <hip/hip_runtime.h>
#include <hip/hip_bf16.h>
#include <stdint.h>

// D-MPNN encoder, fused per-molecule kernel.
// R17: single msg buffer + per-wave 2-slot global_load_lds ring for whf
// (register-free W prefetch) at 2-block/CU residency.
// Register model (fits R6..R16): arch VGPR quantum {64,128,256} + 64 AGPR;
// waves/SIMD = floor(512/total). 128 arch -> 2 waves/SIMD; 129+ -> 1.
// => all changes must keep arch <= 128; 3 waves/SIMD unreachable.

typedef __attribute__((ext_vector_type(8))) short s8v;
typedef __attribute__((ext_vector_type(4))) float f4v;
typedef float f4u __attribute__((ext_vector_type(4), aligned(4)));

__device__ __forceinline__ float u2f(unsigned int u){
  union { unsigned int i; float f; } v; v.i = u; return v.f;
}
__device__ __forceinline__ unsigned short f2bf(float f){
  union { __hip_bfloat16 b; unsigned short u; } cv;
  cv.b = __float2bfloat16(f);
  return cv.u;
}
__device__ __forceinline__ float bf2f(unsigned short u){
  return u2f(((unsigned int)u)<<16);
}
__device__ __forceinline__ void vm5(){ asm volatile("s_waitcnt vmcnt(5)" ::: "memory"); }
__device__ __forceinline__ void vm0(){ asm volatile("s_waitcnt vmcnt(0)" ::: "memory"); }
__device__ __forceinline__ void lk0(){ asm volatile("s_waitcnt lgkmcnt(0)" ::: "memory"); }

// stage one k-step's 5 B-fragments (5120 B) into a ring slot (async, no VGPR dest)
__device__ __forceinline__ void stageW(const unsigned short* __restrict__ wb,
                                       unsigned char* slotbase, int wn0, int lane, int ks){
#pragma unroll
  for (int n=0;n<5;n++){
    const unsigned short* src = wb + (size_t)((ks*20 + wn0 + n)*64 + lane)*8;
    __builtin_amdgcn_global_load_lds(
        (const __attribute__((address_space(1))) void*)src,
        (__attribute__((address_space(3))) void*)(slotbase + n*1024 + lane*16),
        16, 0, 0);
  }
}

// Build MFMA B-fragment layout: frag[ks][nf][lane][8],
//   element = W[k = ks*32 + (lane>>4)*8 + j][n = nf*16 + (lane&15)] (0 outside)
// remap=1 (W_o concat padding): k<133 -> k, 133..143 -> 0, 144..443 -> k-11, else 0.
__global__ void conv_w_k(const float* __restrict__ W, unsigned short* __restrict__ frag,
                         int NS, int K0, int remap)
{
  int id = blockIdx.x*256 + threadIdx.x;
  int total = NS*20*64;
  if (id>=total) return;
  int lane = id & 63;
  int fid = id >> 6;
  int nf = fid % 20, ks = fid / 20;
  int n = nf*16 + (lane & 15);
  int kb = ks*32 + (lane>>4)*8;
  unsigned short o[8];
#pragma unroll
  for (int j=0;j<8;j++){
    int k = kb + j;
    int ksrc;
    if (remap){
      if (k < 133) ksrc = k;
      else if (k < 144) ksrc = -1;
      else if (k < 444) ksrc = k - 11;
      else ksrc = -1;
    } else {
      ksrc = (k < K0) ? k : -1;
    }
    float v = (ksrc >= 0 && n < 300) ? W[(size_t)ksrc*300 + n] : 0.f;
    o[j] = f2bf(v);
  }
  *(s8v*)(frag + (size_t)id*8) = *(const s8v*)o;
}

// LDS regions (71872 B total -> 2 blocks/CU):
//   A @0      (30720): fb staging [48][192] -> msg [48][320] -> (dead)
//   B @30720  (40960): whf ring [4 waves][2 slots][5120] during iterations;
//                      then ain [32][448] (28672); then hid f32 [24][300]
//   oth @71680 (192)
__global__ __launch_bounds__(256) void mpnn_fused(
    const float* __restrict__ f_atoms, const float* __restrict__ f_bonds,
    const int* __restrict__ a2b, const int* __restrict__ b2a,
    const int* __restrict__ b2revb,
    const unsigned short* __restrict__ wif, const unsigned short* __restrict__ whf,
    const unsigned short* __restrict__ wof, const float* __restrict__ b_o,
    float* __restrict__ out)
{
  __shared__ unsigned char L[71872];
  unsigned short* MB  = (unsigned short*)L;             // msg [48][320] swizzled
  unsigned char* ringB = L + 30720;                     // [4][2][5120]
  unsigned short* ain = (unsigned short*)(L + 30720);   // [32][448] swizzled (after iters)
  float* hid = (float*)(L + 30720);                     // [24][300] f32 (after GEMM3)
  int* oth = (int*)(L + 71680);                         // [48]

  const int tid  = threadIdx.x;
  const int lane = tid & 63;
  const int w    = tid >> 6;
  const int lrow = lane & 15;
  const int kq   = lane >> 4;
  const int wn0  = w*5;
  const int blk  = blockIdx.x;
  const int gb0  = 48*blk + 1;   // first global bond of this molecule
  const int ga0  = 24*blk + 1;   // first global atom
  unsigned char* myring = ringB + w*10240;

  // ---- per-bond "other" index (local) ----
  if (tid < 48){
    int gb = gb0 + tid;
    int u = b2a[gb];
    oth[tid] = a2b[2*u] + a2b[2*u+1] - b2revb[gb] - gb0;
  }
  // ---- stage f_bonds -> bf16 LDS A [48][24 chunks], swizzled ----
  for (int c = tid; c < 48*24; c += 256){
    int row = c/24, ch = c - row*24;
    const float* sp = f_bonds + (size_t)(gb0+row)*147 + ch*8;
    unsigned short o[8];
    if (ch < 18){
      f4u v0 = *(const f4u*)(sp);
      f4u v1 = *(const f4u*)(sp+4);
#pragma unroll
      for (int j=0;j<4;j++){ o[j] = f2bf(v0[j]); o[4+j] = f2bf(v1[j]); }
    } else if (ch == 18){
#pragma unroll
      for (int j=0;j<8;j++) o[j] = f2bf((144+j) < 147 ? sp[j] : 0.f);
    } else {
#pragma unroll
      for (int j=0;j<8;j++) o[j] = 0;
    }
    *(s8v*)(MB + (size_t)row*192 + (((ch^(row&7))<<3))) = *(const s8v*)o;
  }
  __syncthreads();

  // ---- GEMM0: inp = fb @ W_i  (K_real=147 -> 5 k-steps), plain loads ----
  f4v acc[3][5];
#pragma unroll
  for (int mf=0;mf<3;mf++)
#pragma unroll
    for (int n=0;n<5;n++) acc[mf][n] = (f4v){0.f,0.f,0.f,0.f};

#pragma unroll 1
  for (int ks=0; ks<5; ks++){
    const unsigned short* wp = wif + ((size_t)(ks*20 + wn0)*64 + lane)*8;
    s8v bfr[5];
#pragma unroll
    for (int n=0;n<5;n++) bfr[n] = *(const s8v*)(wp + n*512);
    s8v af[3];
#pragma unroll
    for (int mf=0;mf<3;mf++){
      int row = mf*16 + lrow;
      af[mf] = *(const s8v*)(MB + (size_t)row*192 + (((ks*4+kq)^(row&7))<<3));
    }
#pragma unroll
    for (int n=0;n<5;n++)
#pragma unroll
      for (int mf=0;mf<3;mf++)
        acc[mf][n] = __builtin_amdgcn_mfma_f32_16x16x32_bf16(af[mf], bfr[n], acc[mf][n], 0,0,0);
  }
  __syncthreads();   // fb reads done; A reusable as msg

  // ---- inp -> packed-bf16 regs; msg0 = relu(inp) -> A ----
  unsigned int inpP0[3][5], inpP1[3][5];
#pragma unroll
  for (int mf=0;mf<3;mf++){
#pragma unroll
    for (int n=0;n<5;n++){
      inpP0[mf][n] = (unsigned)f2bf(acc[mf][n][0]) | ((unsigned)f2bf(acc[mf][n][1])<<16);
      inpP1[mf][n] = (unsigned)f2bf(acc[mf][n][2]) | ((unsigned)f2bf(acc[mf][n][3])<<16);
      int col = (wn0+n)*16 + lrow;
#pragma unroll
      for (int r=0;r<4;r++){
        int row = mf*16 + kq*4 + r;
        float v = acc[mf][n][r];
        MB[(size_t)row*320 + (((col>>3)^(row&7))<<3) + (col&7)] = f2bf(v>0.f ? v : 0.f);
      }
    }
  }
  __syncthreads();

  const int g0 = oth[lrow], g1 = oth[16+lrow], g2 = oth[32+lrow];

  // ---- 5 message-update iterations; whf via per-wave 2-slot LDS ring ----
#pragma unroll 1
  for (int it=0; it<5; ++it){
    // acc init = inp residual
#pragma unroll
    for (int mf=0;mf<3;mf++)
#pragma unroll
      for (int n=0;n<5;n++){
        unsigned int p0 = inpP0[mf][n], p1 = inpP1[mf][n];
        acc[mf][n][0] = u2f(p0<<16);
        acc[mf][n][1] = u2f(p0 & 0xffff0000u);
        acc[mf][n][2] = u2f(p1<<16);
        acc[mf][n][3] = u2f(p1 & 0xffff0000u);
      }

    stageW(whf, myring,        wn0, lane, 0);
    stageW(whf, myring + 5120, wn0, lane, 1);
#pragma unroll 1
    for (int ks=0; ks<10; ks++){
      if (ks < 9) vm5(); else vm0();      // stage(ks) complete; stage(ks+1) may fly
      const unsigned short* rp = (const unsigned short*)(myring + (ks&1)*5120 + lane*16);
      s8v bfr[5];
#pragma unroll
      for (int n=0;n<5;n++) bfr[n] = *(const s8v*)(rp + n*512);
      s8v af[3];
      af[0] = *(const s8v*)(MB + (size_t)g0*320 + (((ks*4+kq)^(g0&7))<<3));
      af[1] = *(const s8v*)(MB + (size_t)g1*320 + (((ks*4+kq)^(g1&7))<<3));
      af[2] = *(const s8v*)(MB + (size_t)g2*320 + (((ks*4+kq)^(g2&7))<<3));
      lk0();                              // reads retired before slot overwrite
      if (ks < 8) stageW(whf, myring + (ks&1)*5120, wn0, lane, ks+2);
#pragma unroll
      for (int n=0;n<5;n++)
#pragma unroll
        for (int mf=0;mf<3;mf++)
          acc[mf][n] = __builtin_amdgcn_mfma_f32_16x16x32_bf16(af[mf], bfr[n], acc[mf][n], 0,0,0);
    }
    __syncthreads();   // all old-msg reads complete before overwrite
#pragma unroll
    for (int mf=0;mf<3;mf++){
#pragma unroll
      for (int n=0;n<5;n++){
        int col = (wn0+n)*16 + lrow;
#pragma unroll
        for (int r=0;r<4;r++){
          int row = mf*16 + kq*4 + r;
          float v = acc[mf][n][r];
          MB[(size_t)row*320 + (((col>>3)^(row&7))<<3) + (col&7)] = f2bf(v>0.f ? v : 0.f);
        }
      }
    }
    __syncthreads();
  }

  // ---- stage a_in = [f_atoms | 0 | amsg | 0] into B-as-ain [32][56 ch] ----
  // (ring drained: last k-step did vmcnt(0); reads retired before this barrier)
  for (int c = tid; c < 32*56; c += 256){
    int row = c/56, ch = c - row*56;
    unsigned short o[8];
#pragma unroll
    for (int j=0;j<8;j++) o[j] = 0;
    if (row < 24){
      if (ch < 16){
        const float* ap = f_atoms + (size_t)(ga0+row)*133 + ch*8;
        f4u v0 = *(const f4u*)(ap);
        f4u v1 = *(const f4u*)(ap+4);
#pragma unroll
        for (int j=0;j<4;j++){ o[j] = f2bf(v0[j]); o[4+j] = f2bf(v1[j]); }
      } else if (ch == 16){
        const float* ap = f_atoms + (size_t)(ga0+row)*133 + 128;
#pragma unroll
        for (int j=0;j<8;j++) o[j] = f2bf((128+j) < 133 ? ap[j] : 0.f);
      } else if (ch >= 18){
        int q = ch - 18;
        int r2 = 2*row, r3 = 2*row+1;
        s8v a = *(const s8v*)(MB + (size_t)r2*320 + ((q^(r2&7))<<3));
        s8v b = *(const s8v*)(MB + (size_t)r3*320 + ((q^(r3&7))<<3));
#pragma unroll
        for (int j=0;j<8;j++)
          o[j] = f2bf(bf2f((unsigned short)a[j]) + bf2f((unsigned short)b[j]));
      }
    }
    *(s8v*)(ain + (size_t)row*448 + ((ch^(row&7))<<3)) = *(const s8v*)o;
  }
  __syncthreads();

  // ---- GEMM3: hid = relu(a_in @ W_o + b_o)  (K=448, 14 k-steps, M=32 pad) ----
  f4v acc2[2][5];
#pragma unroll
  for (int mf=0;mf<2;mf++)
#pragma unroll
    for (int n=0;n<5;n++) acc2[mf][n] = (f4v){0.f,0.f,0.f,0.f};

#pragma unroll 1
  for (int ks=0; ks<14; ks++){
    const unsigned short* wp = wof + ((size_t)(ks*20 + wn0)*64 + lane)*8;
    s8v bfr[5];
#pragma unroll
    for (int n=0;n<5;n++) bfr[n] = *(const s8v*)(wp + n*512);
    s8v af[2];
#pragma unroll
    for (int mf=0;mf<2;mf++){
      int row = mf*16 + lrow;
      af[mf] = *(const s8v*)(ain + (size_t)row*448 + (((ks*4+kq)^(row&7))<<3));
    }
#pragma unroll
    for (int n=0;n<5;n++)
#pragma unroll
      for (int mf=0;mf<2;mf++)
        acc2[mf][n] = __builtin_amdgcn_mfma_f32_16x16x32_bf16(af[mf], bfr[n], acc2[mf][n], 0,0,0);
  }
  __syncthreads();   // all ain reads done before hid overwrites region B

#pragma unroll
  for (int mf=0;mf<2;mf++){
#pragma unroll
    for (int n=0;n<5;n++){
      int col = (wn0+n)*16 + lrow;
      if (col < 300){
        float bo = b_o[col];
#pragma unroll
        for (int r=0;r<4;r++){
          int row = mf*16 + kq*4 + r;
          if (row < 24){
            float v = acc2[mf][n][r] + bo;
            hid[row*300 + col] = v>0.f ? v : 0.f;
          }
        }
      }
    }
  }
  __syncthreads();

  // ---- per-molecule mean over 24 atoms ----
  for (int c = tid; c < 300; c += 256){
    float s = 0.f;
#pragma unroll
    for (int a=0;a<24;a++) s += hid[a*300 + c];
    out[(size_t)blk*300 + c] = s * (1.0f/24.0f);
  }
}

extern "C" void kernel_launch(void* const* d_in, const int* in_sizes, int n_in,
                              void* d_out, int out_size, void* d_ws, size_t ws_size,
                              hipStream_t stream)
{
  const float* f_atoms = (const float*)d_in[0];
  const float* f_bonds = (const float*)d_in[1];
  const int* a2b    = (const int*)d_in[2];
  const int* b2a    = (const int*)d_in[4];
  const int* b2revb = (const int*)d_in[5];
  const float* W_i = (const float*)d_in[8];
  const float* W_h = (const float*)d_in[9];
  const float* W_o = (const float*)d_in[10];
  const float* b_o = (const float*)d_in[11];

  const int NA   = in_sizes[2] / 2;   // 49153 (incl dummy atom 0)
  const int MOLS = (NA - 1) / 24;     // 2048

  // workspace: W fragment buffers only (~600 KB)
  unsigned short* wif = (unsigned short*)d_ws;               // 5 k-steps
  unsigned short* whf = wif + (size_t)5*20*64*8;             // 10 k-steps
  unsigned short* wof = whf + (size_t)10*20*64*8;            // 14 k-steps
  (void)ws_size; (void)n_in; (void)out_size;

  hipLaunchKernelGGL(conv_w_k, dim3((5*20*64+255)/256),  dim3(256), 0, stream, W_i, wif, 5, 147, 0);
  hipLaunchKernelGGL(conv_w_k, dim3((10*20*64+255)/256), dim3(256), 0, stream, W_h, whf, 10, 300, 0);
  hipLaunchKernelGGL(conv_w_k, dim3((14*20*64+255)/256), dim3(256), 0, stream, W_o, wof, 14, 433, 1);

  hipLaunchKernelGGL(mpnn_fused, dim3(MOLS), dim3(256), 0, stream,
                     f_atoms, f_bonds, a2b, b2a, b2revb,
                     wif, whf, wof, b_o, (float*)d_out);
}

// Round 18
// 203.256 us; speedup vs baseline: 1.6914x; 1.6365x over previous
//
#include <hip/hip_runtime.h>
#include <hip/hip_bf16.h>
#include <stdint.h>

// D-MPNN encoder, fused per-molecule kernel (R15 revert + fused W-prep launch).
// Graph facts: ring molecules, 24 atoms / 48 bonds each; other(b) in-molecule;
// a2b[v]={2v-1,2v}; molecule m owns atoms 1+24m.., bonds 1+48m..
// Ledger (counter-verified, 17 rounds):
//   R4-R9: reg working set over cap -> scratch spills (0.3-1.7 GB).
//   R6/R10: full-unroll k-loops -> 208 VGPR -> 1 wave/SIMD, 334 us.
//   R12: unroll-1 k-loops -> 104 VGPR -> 2 blocks/CU, 251 us.
//   R13: inp->acc-init + ping-pong + native cvt -> 227 us (VGPR 128 exact).
//   R14/R16/R17: reg-pipeline/single-buffer/LDS-ring each added 4-20 arch
//     VGPRs -> quantum jump past 128 -> 1 block/CU -> 297/344/333 us.
//   R15: GEMM0 5 k-steps + vectorized staging -> 212 us. BEST.
// REGISTER MODEL (closed): arch quantum {64,128,256} + 64 AGPR acc;
//   waves/SIMD = floor(512/(arch_quantum+64)). 128 arch <=> 2 waves/SIMD (max).
//   R15 sits at 128 exactly; zero register slack exists for prefetching.
// R18: R15 verbatim; the three conv_w_k prep launches fused into one kernel.

typedef __attribute__((ext_vector_type(8))) short s8v;
typedef __attribute__((ext_vector_type(4))) float f4v;
typedef float f4u __attribute__((ext_vector_type(4), aligned(4)));  // unaligned-ok vec load

__device__ __forceinline__ float u2f(unsigned int u){
  union { unsigned int i; float f; } v; v.i = u; return v.f;
}
__device__ __forceinline__ unsigned short f2bf(float f){
  union { __hip_bfloat16 b; unsigned short u; } cv;
  cv.b = __float2bfloat16(f);           // hardware RNE
  return cv.u;
}
__device__ __forceinline__ float bf2f(unsigned short u){
  return u2f(((unsigned int)u)<<16);
}

// Fused W-fragment builder: one launch prepares wif (5 ks), whf (10 ks),
// wof (14 ks, concat remap). frag layout: [ks][nf][lane][8] with
//   element = W[k = ks*32 + (lane>>4)*8 + j][n = nf*16 + (lane&15)] (0 outside).
__global__ void conv_w_all(const float* __restrict__ W_i, const float* __restrict__ W_h,
                           const float* __restrict__ W_o, unsigned short* __restrict__ ws)
{
  int id = blockIdx.x*256 + threadIdx.x;
  const int T1 = 5*20*64, T2 = T1 + 10*20*64, T3 = T2 + 14*20*64;
  if (id >= T3) return;
  const float* W; int fid; int K0; int remap = 0;
  unsigned short* dst = ws + (size_t)id*8;
  if (id < T1){ W = W_i; fid = id;       K0 = 147; }
  else if (id < T2){ W = W_h; fid = id - T1; K0 = 300; }
  else { W = W_o; fid = id - T2; K0 = 444; remap = 1; }
  int lane = fid & 63;
  int f2 = fid >> 6;
  int nf = f2 % 20, ks = f2 / 20;
  int n = nf*16 + (lane & 15);
  int kb = ks*32 + (lane>>4)*8;
  unsigned short o[8];
#pragma unroll
  for (int j=0;j<8;j++){
    int k = kb + j;
    int ksrc;
    if (remap){
      if (k < 133) ksrc = k;
      else if (k < 144) ksrc = -1;
      else if (k < 444) ksrc = k - 11;
      else ksrc = -1;
    } else {
      ksrc = (k < K0) ? k : -1;
    }
    float v = (ksrc >= 0 && n < 300) ? W[(size_t)ksrc*300 + n] : 0.f;
    o[j] = f2bf(v);
  }
  *(s8v*)dst = *(const s8v*)o;
}

// Fused per-molecule MPNN. 256 threads = 4 waves (1M x 4N); per wave all M rows
// x 80 cols (5 nf). LDS: ping-pong B0/B1 [48][320] bf16 (chunk^=row&7 swizzle)
// + oth[48]. B0 doubles as fb staging [48][192] and hid f32; B1 doubles as ain.
// inp residual in 30 packed-bf16 VGPRs, folded into acc init.
__global__ __launch_bounds__(256) void mpnn_fused(
    const float* __restrict__ f_atoms, const float* __restrict__ f_bonds,
    const int* __restrict__ a2b, const int* __restrict__ b2a,
    const int* __restrict__ b2revb,
    const unsigned short* __restrict__ wif, const unsigned short* __restrict__ whf,
    const unsigned short* __restrict__ wof, const float* __restrict__ b_o,
    float* __restrict__ out)
{
  __shared__ unsigned char L[61632];
  unsigned short* B0 = (unsigned short*)L;              // [48][320] swizzled
  unsigned short* B1 = (unsigned short*)(L + 30720);    // [48][320] swizzled
  int* oth = (int*)(L + 61440);                         // [48]
  unsigned short* ain = B1;                             // [32][448] swizzled (after iters)
  float* hid = (float*)B0;                              // [24][300] f32 (after ain staging)

  const int tid  = threadIdx.x;
  const int lane = tid & 63;
  const int w    = tid >> 6;
  const int lrow = lane & 15;
  const int kq   = lane >> 4;
  const int wn0  = w*5;
  const int blk  = blockIdx.x;
  const int gb0  = 48*blk + 1;   // first global bond of this molecule
  const int ga0  = 24*blk + 1;   // first global atom

  // ---- per-bond "other" index (local) ----
  if (tid < 48){
    int gb = gb0 + tid;
    int u = b2a[gb];
    oth[tid] = a2b[2*u] + a2b[2*u+1] - b2revb[gb] - gb0;
  }
  // ---- stage f_bonds -> bf16 LDS B0 [48][24 chunks], swizzled ----
  for (int c = tid; c < 48*24; c += 256){
    int row = c/24, ch = c - row*24;
    const float* sp = f_bonds + (size_t)(gb0+row)*147 + ch*8;
    unsigned short o[8];
    if (ch < 18){
      f4u v0 = *(const f4u*)(sp);
      f4u v1 = *(const f4u*)(sp+4);
#pragma unroll
      for (int j=0;j<4;j++){ o[j] = f2bf(v0[j]); o[4+j] = f2bf(v1[j]); }
    } else if (ch == 18){
#pragma unroll
      for (int j=0;j<8;j++) o[j] = f2bf((144+j) < 147 ? sp[j] : 0.f);
    } else {
#pragma unroll
      for (int j=0;j<8;j++) o[j] = 0;
    }
    *(s8v*)(B0 + (size_t)row*192 + (((ch^(row&7))<<3))) = *(const s8v*)o;
  }
  __syncthreads();

  // ---- GEMM0: inp = fb @ W_i  (K_real=147 -> 5 k-steps of 32), fb in B0 ----
  f4v acc[3][5];
#pragma unroll
  for (int mf=0;mf<3;mf++)
#pragma unroll
    for (int n=0;n<5;n++) acc[mf][n] = (f4v){0.f,0.f,0.f,0.f};

#pragma unroll 1
  for (int ks=0; ks<5; ks++){
    const unsigned short* wp = wif + ((size_t)(ks*20 + wn0)*64 + lane)*8;
    s8v bfr[5];
#pragma unroll
    for (int n=0;n<5;n++) bfr[n] = *(const s8v*)(wp + n*512);
    s8v af[3];
#pragma unroll
    for (int mf=0;mf<3;mf++){
      int row = mf*16 + lrow;
      af[mf] = *(const s8v*)(B0 + (size_t)row*192 + (((ks*4+kq)^(row&7))<<3));
    }
#pragma unroll
    for (int n=0;n<5;n++)
#pragma unroll
      for (int mf=0;mf<3;mf++)
        acc[mf][n] = __builtin_amdgcn_mfma_f32_16x16x32_bf16(af[mf], bfr[n], acc[mf][n], 0,0,0);
  }

  // ---- inp -> packed-bf16 regs; msg0 = relu(inp) -> B1 ----
  unsigned int inpP0[3][5], inpP1[3][5];   // [r0|r1<<16], [r2|r3<<16]
#pragma unroll
  for (int mf=0;mf<3;mf++){
#pragma unroll
    for (int n=0;n<5;n++){
      inpP0[mf][n] = (unsigned)f2bf(acc[mf][n][0]) | ((unsigned)f2bf(acc[mf][n][1])<<16);
      inpP1[mf][n] = (unsigned)f2bf(acc[mf][n][2]) | ((unsigned)f2bf(acc[mf][n][3])<<16);
      int col = (wn0+n)*16 + lrow;
#pragma unroll
      for (int r=0;r<4;r++){
        int row = mf*16 + kq*4 + r;
        float v = acc[mf][n][r];
        B1[(size_t)row*320 + (((col>>3)^(row&7))<<3) + (col&7)] = f2bf(v>0.f ? v : 0.f);
      }
    }
  }
  __syncthreads();

  const int g0 = oth[lrow], g1 = oth[16+lrow], g2 = oth[32+lrow];

  // ---- 5 message-update iterations, ping-pong B1->B0->B1->B0->B1->B0 ----
#pragma unroll 1
  for (int it=0; it<5; ++it){
    const unsigned short* rd = (it&1) ? B0 : B1;
    unsigned short*       wr = (it&1) ? B1 : B0;
    // acc init = inp residual
#pragma unroll
    for (int mf=0;mf<3;mf++)
#pragma unroll
      for (int n=0;n<5;n++){
        unsigned int p0 = inpP0[mf][n], p1 = inpP1[mf][n];
        acc[mf][n][0] = u2f(p0<<16);
        acc[mf][n][1] = u2f(p0 & 0xffff0000u);
        acc[mf][n][2] = u2f(p1<<16);
        acc[mf][n][3] = u2f(p1 & 0xffff0000u);
      }

#pragma unroll 1
    for (int ks=0; ks<10; ks++){
      const unsigned short* wp = whf + ((size_t)(ks*20 + wn0)*64 + lane)*8;
      s8v bfr[5];
#pragma unroll
      for (int n=0;n<5;n++) bfr[n] = *(const s8v*)(wp + n*512);
      s8v af[3];
      af[0] = *(const s8v*)(rd + (size_t)g0*320 + (((ks*4+kq)^(g0&7))<<3));
      af[1] = *(const s8v*)(rd + (size_t)g1*320 + (((ks*4+kq)^(g1&7))<<3));
      af[2] = *(const s8v*)(rd + (size_t)g2*320 + (((ks*4+kq)^(g2&7))<<3));
#pragma unroll
      for (int n=0;n<5;n++)
#pragma unroll
        for (int mf=0;mf<3;mf++)
          acc[mf][n] = __builtin_amdgcn_mfma_f32_16x16x32_bf16(af[mf], bfr[n], acc[mf][n], 0,0,0);
    }
    // epilogue: msg_new = relu(acc) -> other buffer
#pragma unroll
    for (int mf=0;mf<3;mf++){
#pragma unroll
      for (int n=0;n<5;n++){
        int col = (wn0+n)*16 + lrow;
#pragma unroll
        for (int r=0;r<4;r++){
          int row = mf*16 + kq*4 + r;
          float v = acc[mf][n][r];
          wr[(size_t)row*320 + (((col>>3)^(row&7))<<3) + (col&7)] = f2bf(v>0.f ? v : 0.f);
        }
      }
    }
    __syncthreads();
  }
  // final msg in B0 (it=4 wrote B0)

  // ---- stage a_in = [f_atoms | 0 | amsg | 0] into B1-as-ain [32][56 ch] ----
  for (int c = tid; c < 32*56; c += 256){
    int row = c/56, ch = c - row*56;
    unsigned short o[8];
#pragma unroll
    for (int j=0;j<8;j++) o[j] = 0;
    if (row < 24){
      if (ch < 16){
        const float* ap = f_atoms + (size_t)(ga0+row)*133 + ch*8;
        f4u v0 = *(const f4u*)(ap);
        f4u v1 = *(const f4u*)(ap+4);
#pragma unroll
        for (int j=0;j<4;j++){ o[j] = f2bf(v0[j]); o[4+j] = f2bf(v1[j]); }
      } else if (ch == 16){
        const float* ap = f_atoms + (size_t)(ga0+row)*133 + 128;
#pragma unroll
        for (int j=0;j<8;j++) o[j] = f2bf((128+j) < 133 ? ap[j] : 0.f);
      } else if (ch >= 18){
        int q = ch - 18;
        int r2 = 2*row, r3 = 2*row+1;
        s8v a = *(const s8v*)(B0 + (size_t)r2*320 + ((q^(r2&7))<<3));
        s8v b = *(const s8v*)(B0 + (size_t)r3*320 + ((q^(r3&7))<<3));
#pragma unroll
        for (int j=0;j<8;j++)
          o[j] = f2bf(bf2f((unsigned short)a[j]) + bf2f((unsigned short)b[j]));
      }
    }
    *(s8v*)(ain + (size_t)row*448 + ((ch^(row&7))<<3)) = *(const s8v*)o;
  }
  __syncthreads();

  // ---- GEMM3: hid = relu(a_in @ W_o + b_o)  (K=448, 14 k-steps, M=32 incl pad) ----
  f4v acc2[2][5];
#pragma unroll
  for (int mf=0;mf<2;mf++)
#pragma unroll
    for (int n=0;n<5;n++) acc2[mf][n] = (f4v){0.f,0.f,0.f,0.f};

#pragma unroll 1
  for (int ks=0; ks<14; ks++){
    const unsigned short* wp = wof + ((size_t)(ks*20 + wn0)*64 + lane)*8;
    s8v bfr[5];
#pragma unroll
    for (int n=0;n<5;n++) bfr[n] = *(const s8v*)(wp + n*512);
    s8v af[2];
#pragma unroll
    for (int mf=0;mf<2;mf++){
      int row = mf*16 + lrow;
      af[mf] = *(const s8v*)(ain + (size_t)row*448 + (((ks*4+kq)^(row&7))<<3));
    }
#pragma unroll
    for (int n=0;n<5;n++)
#pragma unroll
      for (int mf=0;mf<2;mf++)
        acc2[mf][n] = __builtin_amdgcn_mfma_f32_16x16x32_bf16(af[mf], bfr[n], acc2[mf][n], 0,0,0);
  }
  // B0 fully consumed -> hid f32
#pragma unroll
  for (int mf=0;mf<2;mf++){
#pragma unroll
    for (int n=0;n<5;n++){
      int col = (wn0+n)*16 + lrow;
      if (col < 300){
        float bo = b_o[col];
#pragma unroll
        for (int r=0;r<4;r++){
          int row = mf*16 + kq*4 + r;
          if (row < 24){
            float v = acc2[mf][n][r] + bo;
            hid[row*300 + col] = v>0.f ? v : 0.f;
          }
        }
      }
    }
  }
  __syncthreads();

  // ---- per-molecule mean over 24 atoms ----
  for (int c = tid; c < 300; c += 256){
    float s = 0.f;
#pragma unroll
    for (int a=0;a<24;a++) s += hid[a*300 + c];
    out[(size_t)blk*300 + c] = s * (1.0f/24.0f);
  }
}

extern "C" void kernel_launch(void* const* d_in, const int* in_sizes, int n_in,
                              void* d_out, int out_size, void* d_ws, size_t ws_size,
                              hipStream_t stream)
{
  const float* f_atoms = (const float*)d_in[0];
  const float* f_bonds = (const float*)d_in[1];
  const int* a2b    = (const int*)d_in[2];
  const int* b2a    = (const int*)d_in[4];
  const int* b2revb = (const int*)d_in[5];
  const float* W_i = (const float*)d_in[8];
  const float* W_h = (const float*)d_in[9];
  const float* W_o = (const float*)d_in[10];
  const float* b_o = (const float*)d_in[11];

  const int NA   = in_sizes[2] / 2;   // 49153 (incl dummy atom 0)
  const int MOLS = (NA - 1) / 24;     // 2048

  // workspace: W fragment buffers, contiguous: wif(5) | whf(10) | wof(14) k-steps
  unsigned short* wif = (unsigned short*)d_ws;
  unsigned short* whf = wif + (size_t)5*20*64*8;
  unsigned short* wof = whf + (size_t)10*20*64*8;
  (void)ws_size; (void)n_in; (void)out_size;

  const int WTOT = (5+10+14)*20*64;   // 37120 threads
  hipLaunchKernelGGL(conv_w_all, dim3((WTOT+255)/256), dim3(256), 0, stream,
                     W_i, W_h, W_o, wif);

  hipLaunchKernelGGL(mpnn_fused, dim3(MOLS), dim3(256), 0, stream,
                     f_atoms, f_bonds, a2b, b2a, b2revb,
                     wif, whf, wof, b_o, (float*)d_out);
}

// Round 19
// 182.496 us; speedup vs baseline: 1.8838x; 1.1138x over previous
//
#include <hip/hip_runtime.h>
#include <hip/hip_bf16.h>
#include <stdint.h>

// D-MPNN encoder, fused per-molecule kernel (R18 + s_setprio around MFMA).
// Graph facts: ring molecules, 24 atoms / 48 bonds each; other(b) in-molecule;
// a2b[v]={2v-1,2v}; molecule m owns atoms 1+24m.., bonds 1+48m..
// Ledger (counter-verified, 18 rounds):
//   R4-R9: reg working set over cap -> scratch spills (0.3-1.7 GB).
//   R6/R10: full-unroll k-loops -> 208 VGPR -> 1 wave/SIMD, 334 us.
//   R12: unroll-1 k-loops -> 104 VGPR -> 2 blocks/CU, 251 us.
//   R13: inp->acc-init + ping-pong + native cvt -> 227 us (VGPR 128 exact).
//   R14/R16/R17: each latency-hiding attempt added 4-20 arch VGPRs ->
//     quantum past 128 -> 1 block/CU -> 297/344/333 us.
//   R15: GEMM0 5 k-steps + vectorized staging -> 212 us.
//   R18: fused W-prep launch -> 203 us. VGPR 128, occ 22%.
// REGISTER MODEL (closed, fits all 18 pts): waves/SIMD =
//   floor(256 / ceil64(arch VGPR_Count)); <=128 <=> 2 waves/SIMD (hard max);
//   AGPR acc (60) rides in the unified file. Zero arch slack at 128.
// R19: s_setprio(1) around MFMA clusters (T5; register-free). The 2 resident
//   waves/SIMD are from DIFFERENT blocks (unsynced -> phase diversity),
//   the regime where setprio measured +4-7% (m191).

typedef __attribute__((ext_vector_type(8))) short s8v;
typedef __attribute__((ext_vector_type(4))) float f4v;
typedef float f4u __attribute__((ext_vector_type(4), aligned(4)));  // unaligned-ok vec load

__device__ __forceinline__ float u2f(unsigned int u){
  union { unsigned int i; float f; } v; v.i = u; return v.f;
}
__device__ __forceinline__ unsigned short f2bf(float f){
  union { __hip_bfloat16 b; unsigned short u; } cv;
  cv.b = __float2bfloat16(f);           // hardware RNE
  return cv.u;
}
__device__ __forceinline__ float bf2f(unsigned short u){
  return u2f(((unsigned int)u)<<16);
}

// Fused W-fragment builder: one launch prepares wif (5 ks), whf (10 ks),
// wof (14 ks, concat remap). frag layout: [ks][nf][lane][8] with
//   element = W[k = ks*32 + (lane>>4)*8 + j][n = nf*16 + (lane&15)] (0 outside).
__global__ void conv_w_all(const float* __restrict__ W_i, const float* __restrict__ W_h,
                           const float* __restrict__ W_o, unsigned short* __restrict__ ws)
{
  int id = blockIdx.x*256 + threadIdx.x;
  const int T1 = 5*20*64, T2 = T1 + 10*20*64, T3 = T2 + 14*20*64;
  if (id >= T3) return;
  const float* W; int fid; int K0; int remap = 0;
  unsigned short* dst = ws + (size_t)id*8;
  if (id < T1){ W = W_i; fid = id;       K0 = 147; }
  else if (id < T2){ W = W_h; fid = id - T1; K0 = 300; }
  else { W = W_o; fid = id - T2; K0 = 444; remap = 1; }
  int lane = fid & 63;
  int f2 = fid >> 6;
  int nf = f2 % 20, ks = f2 / 20;
  int n = nf*16 + (lane & 15);
  int kb = ks*32 + (lane>>4)*8;
  unsigned short o[8];
#pragma unroll
  for (int j=0;j<8;j++){
    int k = kb + j;
    int ksrc;
    if (remap){
      if (k < 133) ksrc = k;
      else if (k < 144) ksrc = -1;
      else if (k < 444) ksrc = k - 11;
      else ksrc = -1;
    } else {
      ksrc = (k < K0) ? k : -1;
    }
    float v = (ksrc >= 0 && n < 300) ? W[(size_t)ksrc*300 + n] : 0.f;
    o[j] = f2bf(v);
  }
  *(s8v*)dst = *(const s8v*)o;
}

// Fused per-molecule MPNN. 256 threads = 4 waves (1M x 4N); per wave all M rows
// x 80 cols (5 nf). LDS: ping-pong B0/B1 [48][320] bf16 (chunk^=row&7 swizzle)
// + oth[48]. B0 doubles as fb staging [48][192] and hid f32; B1 doubles as ain.
// inp residual in 30 packed-bf16 VGPRs, folded into acc init.
__global__ __launch_bounds__(256) void mpnn_fused(
    const float* __restrict__ f_atoms, const float* __restrict__ f_bonds,
    const int* __restrict__ a2b, const int* __restrict__ b2a,
    const int* __restrict__ b2revb,
    const unsigned short* __restrict__ wif, const unsigned short* __restrict__ whf,
    const unsigned short* __restrict__ wof, const float* __restrict__ b_o,
    float* __restrict__ out)
{
  __shared__ unsigned char L[61632];
  unsigned short* B0 = (unsigned short*)L;              // [48][320] swizzled
  unsigned short* B1 = (unsigned short*)(L + 30720);    // [48][320] swizzled
  int* oth = (int*)(L + 61440);                         // [48]
  unsigned short* ain = B1;                             // [32][448] swizzled (after iters)
  float* hid = (float*)B0;                              // [24][300] f32 (after ain staging)

  const int tid  = threadIdx.x;
  const int lane = tid & 63;
  const int w    = tid >> 6;
  const int lrow = lane & 15;
  const int kq   = lane >> 4;
  const int wn0  = w*5;
  const int blk  = blockIdx.x;
  const int gb0  = 48*blk + 1;   // first global bond of this molecule
  const int ga0  = 24*blk + 1;   // first global atom

  // ---- per-bond "other" index (local) ----
  if (tid < 48){
    int gb = gb0 + tid;
    int u = b2a[gb];
    oth[tid] = a2b[2*u] + a2b[2*u+1] - b2revb[gb] - gb0;
  }
  // ---- stage f_bonds -> bf16 LDS B0 [48][24 chunks], swizzled ----
  for (int c = tid; c < 48*24; c += 256){
    int row = c/24, ch = c - row*24;
    const float* sp = f_bonds + (size_t)(gb0+row)*147 + ch*8;
    unsigned short o[8];
    if (ch < 18){
      f4u v0 = *(const f4u*)(sp);
      f4u v1 = *(const f4u*)(sp+4);
#pragma unroll
      for (int j=0;j<4;j++){ o[j] = f2bf(v0[j]); o[4+j] = f2bf(v1[j]); }
    } else if (ch == 18){
#pragma unroll
      for (int j=0;j<8;j++) o[j] = f2bf((144+j) < 147 ? sp[j] : 0.f);
    } else {
#pragma unroll
      for (int j=0;j<8;j++) o[j] = 0;
    }
    *(s8v*)(B0 + (size_t)row*192 + (((ch^(row&7))<<3))) = *(const s8v*)o;
  }
  __syncthreads();

  // ---- GEMM0: inp = fb @ W_i  (K_real=147 -> 5 k-steps of 32), fb in B0 ----
  f4v acc[3][5];
#pragma unroll
  for (int mf=0;mf<3;mf++)
#pragma unroll
    for (int n=0;n<5;n++) acc[mf][n] = (f4v){0.f,0.f,0.f,0.f};

#pragma unroll 1
  for (int ks=0; ks<5; ks++){
    const unsigned short* wp = wif + ((size_t)(ks*20 + wn0)*64 + lane)*8;
    s8v bfr[5];
#pragma unroll
    for (int n=0;n<5;n++) bfr[n] = *(const s8v*)(wp + n*512);
    s8v af[3];
#pragma unroll
    for (int mf=0;mf<3;mf++){
      int row = mf*16 + lrow;
      af[mf] = *(const s8v*)(B0 + (size_t)row*192 + (((ks*4+kq)^(row&7))<<3));
    }
    __builtin_amdgcn_s_setprio(1);
#pragma unroll
    for (int n=0;n<5;n++)
#pragma unroll
      for (int mf=0;mf<3;mf++)
        acc[mf][n] = __builtin_amdgcn_mfma_f32_16x16x32_bf16(af[mf], bfr[n], acc[mf][n], 0,0,0);
    __builtin_amdgcn_s_setprio(0);
  }

  // ---- inp -> packed-bf16 regs; msg0 = relu(inp) -> B1 ----
  unsigned int inpP0[3][5], inpP1[3][5];   // [r0|r1<<16], [r2|r3<<16]
#pragma unroll
  for (int mf=0;mf<3;mf++){
#pragma unroll
    for (int n=0;n<5;n++){
      inpP0[mf][n] = (unsigned)f2bf(acc[mf][n][0]) | ((unsigned)f2bf(acc[mf][n][1])<<16);
      inpP1[mf][n] = (unsigned)f2bf(acc[mf][n][2]) | ((unsigned)f2bf(acc[mf][n][3])<<16);
      int col = (wn0+n)*16 + lrow;
#pragma unroll
      for (int r=0;r<4;r++){
        int row = mf*16 + kq*4 + r;
        float v = acc[mf][n][r];
        B1[(size_t)row*320 + (((col>>3)^(row&7))<<3) + (col&7)] = f2bf(v>0.f ? v : 0.f);
      }
    }
  }
  __syncthreads();

  const int g0 = oth[lrow], g1 = oth[16+lrow], g2 = oth[32+lrow];

  // ---- 5 message-update iterations, ping-pong B1->B0->B1->B0->B1->B0 ----
#pragma unroll 1
  for (int it=0; it<5; ++it){
    const unsigned short* rd = (it&1) ? B0 : B1;
    unsigned short*       wr = (it&1) ? B1 : B0;
    // acc init = inp residual
#pragma unroll
    for (int mf=0;mf<3;mf++)
#pragma unroll
      for (int n=0;n<5;n++){
        unsigned int p0 = inpP0[mf][n], p1 = inpP1[mf][n];
        acc[mf][n][0] = u2f(p0<<16);
        acc[mf][n][1] = u2f(p0 & 0xffff0000u);
        acc[mf][n][2] = u2f(p1<<16);
        acc[mf][n][3] = u2f(p1 & 0xffff0000u);
      }

#pragma unroll 1
    for (int ks=0; ks<10; ks++){
      const unsigned short* wp = whf + ((size_t)(ks*20 + wn0)*64 + lane)*8;
      s8v bfr[5];
#pragma unroll
      for (int n=0;n<5;n++) bfr[n] = *(const s8v*)(wp + n*512);
      s8v af[3];
      af[0] = *(const s8v*)(rd + (size_t)g0*320 + (((ks*4+kq)^(g0&7))<<3));
      af[1] = *(const s8v*)(rd + (size_t)g1*320 + (((ks*4+kq)^(g1&7))<<3));
      af[2] = *(const s8v*)(rd + (size_t)g2*320 + (((ks*4+kq)^(g2&7))<<3));
      __builtin_amdgcn_s_setprio(1);
#pragma unroll
      for (int n=0;n<5;n++)
#pragma unroll
        for (int mf=0;mf<3;mf++)
          acc[mf][n] = __builtin_amdgcn_mfma_f32_16x16x32_bf16(af[mf], bfr[n], acc[mf][n], 0,0,0);
      __builtin_amdgcn_s_setprio(0);
    }
    // epilogue: msg_new = relu(acc) -> other buffer
#pragma unroll
    for (int mf=0;mf<3;mf++){
#pragma unroll
      for (int n=0;n<5;n++){
        int col = (wn0+n)*16 + lrow;
#pragma unroll
        for (int r=0;r<4;r++){
          int row = mf*16 + kq*4 + r;
          float v = acc[mf][n][r];
          wr[(size_t)row*320 + (((col>>3)^(row&7))<<3) + (col&7)] = f2bf(v>0.f ? v : 0.f);
        }
      }
    }
    __syncthreads();
  }
  // final msg in B0 (it=4 wrote B0)

  // ---- stage a_in = [f_atoms | 0 | amsg | 0] into B1-as-ain [32][56 ch] ----
  for (int c = tid; c < 32*56; c += 256){
    int row = c/56, ch = c - row*56;
    unsigned short o[8];
#pragma unroll
    for (int j=0;j<8;j++) o[j] = 0;
    if (row < 24){
      if (ch < 16){
        const float* ap = f_atoms + (size_t)(ga0+row)*133 + ch*8;
        f4u v0 = *(const f4u*)(ap);
        f4u v1 = *(const f4u*)(ap+4);
#pragma unroll
        for (int j=0;j<4;j++){ o[j] = f2bf(v0[j]); o[4+j] = f2bf(v1[j]); }
      } else if (ch == 16){
        const float* ap = f_atoms + (size_t)(ga0+row)*133 + 128;
#pragma unroll
        for (int j=0;j<8;j++) o[j] = f2bf((128+j) < 133 ? ap[j] : 0.f);
      } else if (ch >= 18){
        int q = ch - 18;
        int r2 = 2*row, r3 = 2*row+1;
        s8v a = *(const s8v*)(B0 + (size_t)r2*320 + ((q^(r2&7))<<3));
        s8v b = *(const s8v*)(B0 + (size_t)r3*320 + ((q^(r3&7))<<3));
#pragma unroll
        for (int j=0;j<8;j++)
          o[j] = f2bf(bf2f((unsigned short)a[j]) + bf2f((unsigned short)b[j]));
      }
    }
    *(s8v*)(ain + (size_t)row*448 + ((ch^(row&7))<<3)) = *(const s8v*)o;
  }
  __syncthreads();

  // ---- GEMM3: hid = relu(a_in @ W_o + b_o)  (K=448, 14 k-steps, M=32 incl pad) ----
  f4v acc2[2][5];
#pragma unroll
  for (int mf=0;mf<2;mf++)
#pragma unroll
    for (int n=0;n<5;n++) acc2[mf][n] = (f4v){0.f,0.f,0.f,0.f};

#pragma unroll 1
  for (int ks=0; ks<14; ks++){
    const unsigned short* wp = wof + ((size_t)(ks*20 + wn0)*64 + lane)*8;
    s8v bfr[5];
#pragma unroll
    for (int n=0;n<5;n++) bfr[n] = *(const s8v*)(wp + n*512);
    s8v af[2];
#pragma unroll
    for (int mf=0;mf<2;mf++){
      int row = mf*16 + lrow;
      af[mf] = *(const s8v*)(ain + (size_t)row*448 + (((ks*4+kq)^(row&7))<<3));
    }
    __builtin_amdgcn_s_setprio(1);
#pragma unroll
    for (int n=0;n<5;n++)
#pragma unroll
      for (int mf=0;mf<2;mf++)
        acc2[mf][n] = __builtin_amdgcn_mfma_f32_16x16x32_bf16(af[mf], bfr[n], acc2[mf][n], 0,0,0);
    __builtin_amdgcn_s_setprio(0);
  }
  // B0 fully consumed -> hid f32
#pragma unroll
  for (int mf=0;mf<2;mf++){
#pragma unroll
    for (int n=0;n<5;n++){
      int col = (wn0+n)*16 + lrow;
      if (col < 300){
        float bo = b_o[col];
#pragma unroll
        for (int r=0;r<4;r++){
          int row = mf*16 + kq*4 + r;
          if (row < 24){
            float v = acc2[mf][n][r] + bo;
            hid[row*300 + col] = v>0.f ? v : 0.f;
          }
        }
      }
    }
  }
  __syncthreads();

  // ---- per-molecule mean over 24 atoms ----
  for (int c = tid; c < 300; c += 256){
    float s = 0.f;
#pragma unroll
    for (int a=0;a<24;a++) s += hid[a*300 + c];
    out[(size_t)blk*300 + c] = s * (1.0f/24.0f);
  }
}

extern "C" void kernel_launch(void* const* d_in, const int* in_sizes, int n_in,
                              void* d_out, int out_size, void* d_ws, size_t ws_size,
                              hipStream_t stream)
{
  const float* f_atoms = (const float*)d_in[0];
  const float* f_bonds = (const float*)d_in[1];
  const int* a2b    = (const int*)d_in[2];
  const int* b2a    = (const int*)d_in[4];
  const int* b2revb = (const int*)d_in[5];
  const float* W_i = (const float*)d_in[8];
  const float* W_h = (const float*)d_in[9];
  const float* W_o = (const float*)d_in[10];
  const float* b_o = (const float*)d_in[11];

  const int NA   = in_sizes[2] / 2;   // 49153 (incl dummy atom 0)
  const int MOLS = (NA - 1) / 24;     // 2048

  // workspace: W fragment buffers, contiguous: wif(5) | whf(10) | wof(14) k-steps
  unsigned short* wif = (unsigned short*)d_ws;
  unsigned short* whf = wif + (size_t)5*20*64*8;
  unsigned short* wof = whf + (size_t)10*20*64*8;
  (void)ws_size; (void)n_in; (void)out_size;

  const int WTOT = (5+10+14)*20*64;   // 37120 threads
  hipLaunchKernelGGL(conv_w_all, dim3((WTOT+255)/256), dim3(256), 0, stream,
                     W_i, W_h, W_o, wif);

  hipLaunchKernelGGL(mpnn_fused, dim3(MOLS), dim3(256), 0, stream,
                     f_atoms, f_bonds, a2b, b2a, b2revb,
                     wif, whf, wof, b_o, (float*)d_out);
}

// Round 20
// 182.462 us; speedup vs baseline: 1.8841x; 1.0002x over previous
//
#include <hip/hip_runtime.h>
#include <hip/hip_bf16.h>
#include <stdint.h>

// D-MPNN encoder, fused per-molecule kernel (R19 + ds-before-vmem issue order
// + setprio level 2). Final register-free micro-levers.
// Graph facts: ring molecules, 24 atoms / 48 bonds each; other(b) in-molecule;
// a2b[v]={2v-1,2v}; molecule m owns atoms 1+24m.., bonds 1+48m..
// Ledger (counter-verified, 19 rounds):
//   R4-R9: reg working set over cap -> scratch spills (0.3-1.7 GB).
//   R6/R10: full-unroll k-loops -> 208 VGPR -> 1 wave/SIMD, 334 us.
//   R12: unroll-1 k-loops -> 104 VGPR -> 2 blocks/CU, 251 us.
//   R13: inp->acc-init + ping-pong + native cvt -> 227 us (VGPR 128 exact).
//   R14/R16/R17: latency-hiding attempts each cost 4-20 arch VGPRs ->
//     quantum past 128 -> 1 block/CU -> 297/344/333 us. All reverted.
//   R15: GEMM0 5 k-steps + vectorized staging -> 212 us.
//   R18: fused W-prep launch -> 203 us.
//   R19: s_setprio(1) around MFMA clusters -> 182.5 us (+10%; MfmaUtil 26%).
// REGISTER MODEL (closed, 19/19 fits): waves/SIMD = floor(256/ceil64(arch));
//   <=128 arch <=> 2 waves/SIMD (hard max). Zero slack at 128. All
//   register-funded latency-hiding is dead; this round stacks the last two
//   register-free levers (issue order, prio depth).

typedef __attribute__((ext_vector_type(8))) short s8v;
typedef __attribute__((ext_vector_type(4))) float f4v;
typedef float f4u __attribute__((ext_vector_type(4), aligned(4)));  // unaligned-ok vec load

__device__ __forceinline__ float u2f(unsigned int u){
  union { unsigned int i; float f; } v; v.i = u; return v.f;
}
__device__ __forceinline__ unsigned short f2bf(float f){
  union { __hip_bfloat16 b; unsigned short u; } cv;
  cv.b = __float2bfloat16(f);           // hardware RNE
  return cv.u;
}
__device__ __forceinline__ float bf2f(unsigned short u){
  return u2f(((unsigned int)u)<<16);
}

// Fused W-fragment builder: one launch prepares wif (5 ks), whf (10 ks),
// wof (14 ks, concat remap). frag layout: [ks][nf][lane][8] with
//   element = W[k = ks*32 + (lane>>4)*8 + j][n = nf*16 + (lane&15)] (0 outside).
__global__ void conv_w_all(const float* __restrict__ W_i, const float* __restrict__ W_h,
                           const float* __restrict__ W_o, unsigned short* __restrict__ ws)
{
  int id = blockIdx.x*256 + threadIdx.x;
  const int T1 = 5*20*64, T2 = T1 + 10*20*64, T3 = T2 + 14*20*64;
  if (id >= T3) return;
  const float* W; int fid; int K0; int remap = 0;
  unsigned short* dst = ws + (size_t)id*8;
  if (id < T1){ W = W_i; fid = id;       K0 = 147; }
  else if (id < T2){ W = W_h; fid = id - T1; K0 = 300; }
  else { W = W_o; fid = id - T2; K0 = 444; remap = 1; }
  int lane = fid & 63;
  int f2 = fid >> 6;
  int nf = f2 % 20, ks = f2 / 20;
  int n = nf*16 + (lane & 15);
  int kb = ks*32 + (lane>>4)*8;
  unsigned short o[8];
#pragma unroll
  for (int j=0;j<8;j++){
    int k = kb + j;
    int ksrc;
    if (remap){
      if (k < 133) ksrc = k;
      else if (k < 144) ksrc = -1;
      else if (k < 444) ksrc = k - 11;
      else ksrc = -1;
    } else {
      ksrc = (k < K0) ? k : -1;
    }
    float v = (ksrc >= 0 && n < 300) ? W[(size_t)ksrc*300 + n] : 0.f;
    o[j] = f2bf(v);
  }
  *(s8v*)dst = *(const s8v*)o;
}

// Fused per-molecule MPNN. 256 threads = 4 waves (1M x 4N); per wave all M rows
// x 80 cols (5 nf). LDS: ping-pong B0/B1 [48][320] bf16 (chunk^=row&7 swizzle)
// + oth[48]. B0 doubles as fb staging [48][192] and hid f32; B1 doubles as ain.
// inp residual in 30 packed-bf16 VGPRs, folded into acc init.
__global__ __launch_bounds__(256) void mpnn_fused(
    const float* __restrict__ f_atoms, const float* __restrict__ f_bonds,
    const int* __restrict__ a2b, const int* __restrict__ b2a,
    const int* __restrict__ b2revb,
    const unsigned short* __restrict__ wif, const unsigned short* __restrict__ whf,
    const unsigned short* __restrict__ wof, const float* __restrict__ b_o,
    float* __restrict__ out)
{
  __shared__ unsigned char L[61632];
  unsigned short* B0 = (unsigned short*)L;              // [48][320] swizzled
  unsigned short* B1 = (unsigned short*)(L + 30720);    // [48][320] swizzled
  int* oth = (int*)(L + 61440);                         // [48]
  unsigned short* ain = B1;                             // [32][448] swizzled (after iters)
  float* hid = (float*)B0;                              // [24][300] f32 (after ain staging)

  const int tid  = threadIdx.x;
  const int lane = tid & 63;
  const int w    = tid >> 6;
  const int lrow = lane & 15;
  const int kq   = lane >> 4;
  const int wn0  = w*5;
  const int blk  = blockIdx.x;
  const int gb0  = 48*blk + 1;   // first global bond of this molecule
  const int ga0  = 24*blk + 1;   // first global atom

  // ---- per-bond "other" index (local) ----
  if (tid < 48){
    int gb = gb0 + tid;
    int u = b2a[gb];
    oth[tid] = a2b[2*u] + a2b[2*u+1] - b2revb[gb] - gb0;
  }
  // ---- stage f_bonds -> bf16 LDS B0 [48][24 chunks], swizzled ----
  for (int c = tid; c < 48*24; c += 256){
    int row = c/24, ch = c - row*24;
    const float* sp = f_bonds + (size_t)(gb0+row)*147 + ch*8;
    unsigned short o[8];
    if (ch < 18){
      f4u v0 = *(const f4u*)(sp);
      f4u v1 = *(const f4u*)(sp+4);
#pragma unroll
      for (int j=0;j<4;j++){ o[j] = f2bf(v0[j]); o[4+j] = f2bf(v1[j]); }
    } else if (ch == 18){
#pragma unroll
      for (int j=0;j<8;j++) o[j] = f2bf((144+j) < 147 ? sp[j] : 0.f);
    } else {
#pragma unroll
      for (int j=0;j<8;j++) o[j] = 0;
    }
    *(s8v*)(B0 + (size_t)row*192 + (((ch^(row&7))<<3))) = *(const s8v*)o;
  }
  __syncthreads();

  // ---- GEMM0: inp = fb @ W_i  (K_real=147 -> 5 k-steps of 32), fb in B0 ----
  f4v acc[3][5];
#pragma unroll
  for (int mf=0;mf<3;mf++)
#pragma unroll
    for (int n=0;n<5;n++) acc[mf][n] = (f4v){0.f,0.f,0.f,0.f};

#pragma unroll 1
  for (int ks=0; ks<5; ks++){
    s8v af[3];                                   // ds reads first: lgkm drains
#pragma unroll
    for (int mf=0;mf<3;mf++){                    // under the vmem latency below
      int row = mf*16 + lrow;
      af[mf] = *(const s8v*)(B0 + (size_t)row*192 + (((ks*4+kq)^(row&7))<<3));
    }
    const unsigned short* wp = wif + ((size_t)(ks*20 + wn0)*64 + lane)*8;
    s8v bfr[5];
#pragma unroll
    for (int n=0;n<5;n++) bfr[n] = *(const s8v*)(wp + n*512);
    __builtin_amdgcn_s_setprio(2);
#pragma unroll
    for (int n=0;n<5;n++)
#pragma unroll
      for (int mf=0;mf<3;mf++)
        acc[mf][n] = __builtin_amdgcn_mfma_f32_16x16x32_bf16(af[mf], bfr[n], acc[mf][n], 0,0,0);
    __builtin_amdgcn_s_setprio(0);
  }

  // ---- inp -> packed-bf16 regs; msg0 = relu(inp) -> B1 ----
  unsigned int inpP0[3][5], inpP1[3][5];   // [r0|r1<<16], [r2|r3<<16]
#pragma unroll
  for (int mf=0;mf<3;mf++){
#pragma unroll
    for (int n=0;n<5;n++){
      inpP0[mf][n] = (unsigned)f2bf(acc[mf][n][0]) | ((unsigned)f2bf(acc[mf][n][1])<<16);
      inpP1[mf][n] = (unsigned)f2bf(acc[mf][n][2]) | ((unsigned)f2bf(acc[mf][n][3])<<16);
      int col = (wn0+n)*16 + lrow;
#pragma unroll
      for (int r=0;r<4;r++){
        int row = mf*16 + kq*4 + r;
        float v = acc[mf][n][r];
        B1[(size_t)row*320 + (((col>>3)^(row&7))<<3) + (col&7)] = f2bf(v>0.f ? v : 0.f);
      }
    }
  }
  __syncthreads();

  const int g0 = oth[lrow], g1 = oth[16+lrow], g2 = oth[32+lrow];

  // ---- 5 message-update iterations, ping-pong B1->B0->B1->B0->B1->B0 ----
#pragma unroll 1
  for (int it=0; it<5; ++it){
    const unsigned short* rd = (it&1) ? B0 : B1;
    unsigned short*       wr = (it&1) ? B1 : B0;
    // acc init = inp residual
#pragma unroll
    for (int mf=0;mf<3;mf++)
#pragma unroll
      for (int n=0;n<5;n++){
        unsigned int p0 = inpP0[mf][n], p1 = inpP1[mf][n];
        acc[mf][n][0] = u2f(p0<<16);
        acc[mf][n][1] = u2f(p0 & 0xffff0000u);
        acc[mf][n][2] = u2f(p1<<16);
        acc[mf][n][3] = u2f(p1 & 0xffff0000u);
      }

#pragma unroll 1
    for (int ks=0; ks<10; ks++){
      s8v af[3];                                 // ds reads issued first
      af[0] = *(const s8v*)(rd + (size_t)g0*320 + (((ks*4+kq)^(g0&7))<<3));
      af[1] = *(const s8v*)(rd + (size_t)g1*320 + (((ks*4+kq)^(g1&7))<<3));
      af[2] = *(const s8v*)(rd + (size_t)g2*320 + (((ks*4+kq)^(g2&7))<<3));
      const unsigned short* wp = whf + ((size_t)(ks*20 + wn0)*64 + lane)*8;
      s8v bfr[5];
#pragma unroll
      for (int n=0;n<5;n++) bfr[n] = *(const s8v*)(wp + n*512);
      __builtin_amdgcn_s_setprio(2);
#pragma unroll
      for (int n=0;n<5;n++)
#pragma unroll
        for (int mf=0;mf<3;mf++)
          acc[mf][n] = __builtin_amdgcn_mfma_f32_16x16x32_bf16(af[mf], bfr[n], acc[mf][n], 0,0,0);
      __builtin_amdgcn_s_setprio(0);
    }
    // epilogue: msg_new = relu(acc) -> other buffer
#pragma unroll
    for (int mf=0;mf<3;mf++){
#pragma unroll
      for (int n=0;n<5;n++){
        int col = (wn0+n)*16 + lrow;
#pragma unroll
        for (int r=0;r<4;r++){
          int row = mf*16 + kq*4 + r;
          float v = acc[mf][n][r];
          wr[(size_t)row*320 + (((col>>3)^(row&7))<<3) + (col&7)] = f2bf(v>0.f ? v : 0.f);
        }
      }
    }
    __syncthreads();
  }
  // final msg in B0 (it=4 wrote B0)

  // ---- stage a_in = [f_atoms | 0 | amsg | 0] into B1-as-ain [32][56 ch] ----
  for (int c = tid; c < 32*56; c += 256){
    int row = c/56, ch = c - row*56;
    unsigned short o[8];
#pragma unroll
    for (int j=0;j<8;j++) o[j] = 0;
    if (row < 24){
      if (ch < 16){
        const float* ap = f_atoms + (size_t)(ga0+row)*133 + ch*8;
        f4u v0 = *(const f4u*)(ap);
        f4u v1 = *(const f4u*)(ap+4);
#pragma unroll
        for (int j=0;j<4;j++){ o[j] = f2bf(v0[j]); o[4+j] = f2bf(v1[j]); }
      } else if (ch == 16){
        const float* ap = f_atoms + (size_t)(ga0+row)*133 + 128;
#pragma unroll
        for (int j=0;j<8;j++) o[j] = f2bf((128+j) < 133 ? ap[j] : 0.f);
      } else if (ch >= 18){
        int q = ch - 18;
        int r2 = 2*row, r3 = 2*row+1;
        s8v a = *(const s8v*)(B0 + (size_t)r2*320 + ((q^(r2&7))<<3));
        s8v b = *(const s8v*)(B0 + (size_t)r3*320 + ((q^(r3&7))<<3));
#pragma unroll
        for (int j=0;j<8;j++)
          o[j] = f2bf(bf2f((unsigned short)a[j]) + bf2f((unsigned short)b[j]));
      }
    }
    *(s8v*)(ain + (size_t)row*448 + ((ch^(row&7))<<3)) = *(const s8v*)o;
  }
  __syncthreads();

  // ---- GEMM3: hid = relu(a_in @ W_o + b_o)  (K=448, 14 k-steps, M=32 incl pad) ----
  f4v acc2[2][5];
#pragma unroll
  for (int mf=0;mf<2;mf++)
#pragma unroll
    for (int n=0;n<5;n++) acc2[mf][n] = (f4v){0.f,0.f,0.f,0.f};

#pragma unroll 1
  for (int ks=0; ks<14; ks++){
    s8v af[2];                                   // ds reads issued first
#pragma unroll
    for (int mf=0;mf<2;mf++){
      int row = mf*16 + lrow;
      af[mf] = *(const s8v*)(ain + (size_t)row*448 + (((ks*4+kq)^(row&7))<<3));
    }
    const unsigned short* wp = wof + ((size_t)(ks*20 + wn0)*64 + lane)*8;
    s8v bfr[5];
#pragma unroll
    for (int n=0;n<5;n++) bfr[n] = *(const s8v*)(wp + n*512);
    __builtin_amdgcn_s_setprio(2);
#pragma unroll
    for (int n=0;n<5;n++)
#pragma unroll
      for (int mf=0;mf<2;mf++)
        acc2[mf][n] = __builtin_amdgcn_mfma_f32_16x16x32_bf16(af[mf], bfr[n], acc2[mf][n], 0,0,0);
    __builtin_amdgcn_s_setprio(0);
  }
  // B0 fully consumed -> hid f32
#pragma unroll
  for (int mf=0;mf<2;mf++){
#pragma unroll
    for (int n=0;n<5;n++){
      int col = (wn0+n)*16 + lrow;
      if (col < 300){
        float bo = b_o[col];
#pragma unroll
        for (int r=0;r<4;r++){
          int row = mf*16 + kq*4 + r;
          if (row < 24){
            float v = acc2[mf][n][r] + bo;
            hid[row*300 + col] = v>0.f ? v : 0.f;
          }
        }
      }
    }
  }
  __syncthreads();

  // ---- per-molecule mean over 24 atoms ----
  for (int c = tid; c < 300; c += 256){
    float s = 0.f;
#pragma unroll
    for (int a=0;a<24;a++) s += hid[a*300 + c];
    out[(size_t)blk*300 + c] = s * (1.0f/24.0f);
  }
}

extern "C" void kernel_launch(void* const* d_in, const int* in_sizes, int n_in,
                              void* d_out, int out_size, void* d_ws, size_t ws_size,
                              hipStream_t stream)
{
  const float* f_atoms = (const float*)d_in[0];
  const float* f_bonds = (const float*)d_in[1];
  const int* a2b    = (const int*)d_in[2];
  const int* b2a    = (const int*)d_in[4];
  const int* b2revb = (const int*)d_in[5];
  const float* W_i = (const float*)d_in[8];
  const float* W_h = (const float*)d_in[9];
  const float* W_o = (const float*)d_in[10];
  const float* b_o = (const float*)d_in[11];

  const int NA   = in_sizes[2] / 2;   // 49153 (incl dummy atom 0)
  const int MOLS = (NA - 1) / 24;     // 2048

  // workspace: W fragment buffers, contiguous: wif(5) | whf(10) | wof(14) k-steps
  unsigned short* wif = (unsigned short*)d_ws;
  unsigned short* whf = wif + (size_t)5*20*64*8;
  unsigned short* wof = whf + (size_t)10*20*64*8;
  (void)ws_size; (void)n_in; (void)out_size;

  const int WTOT = (5+10+14)*20*64;   // 37120 threads
  hipLaunchKernelGGL(conv_w_all, dim3((WTOT+255)/256), dim3(256), 0, stream,
                     W_i, W_h, W_o, wif);

  hipLaunchKernelGGL(mpnn_fused, dim3(MOLS), dim3(256), 0, stream,
                     f_atoms, f_bonds, a2b, b2a, b2revb,
                     wif, whf, wof, b_o, (float*)d_out);
}